// Round 5
// baseline (274.984 us; speedup 1.0000x reference)
//
#include <hip/hip_runtime.h>
#include <hip/hip_bf16.h>
#include <stdint.h>

#define N_PTS 16384
#define C_CH  64
#define D_REF 5
#define LOG2E 1.44269504088896340736f
#define IBLOCKS 64        // 256 i per block (8 waves x 2 i-tiles x 16)

typedef __attribute__((ext_vector_type(8))) short bf16x8;
typedef __attribute__((ext_vector_type(4))) float f32x4;

__device__ __forceinline__ unsigned short bf16rn(float v) {
    unsigned u = __builtin_bit_cast(unsigned, v) + 0x8000u;   // round-half-up
    return (unsigned short)(u >> 16);
}
__device__ __forceinline__ float bf16tof(unsigned x) {
    return __builtin_bit_cast(float, x << 16);
}
__device__ __forceinline__ unsigned pack2bf16(float lo, float hi) {
    unsigned a = __builtin_bit_cast(unsigned, lo) + 0x8000u;
    unsigned b = __builtin_bit_cast(unsigned, hi) + 0x8000u;
    return __builtin_amdgcn_perm(b, a, 0x07060302u);
}
__device__ __forceinline__ unsigned cvt2(float lo, float hi) {
#if __has_builtin(__builtin_amdgcn_cvt_pk_bf16_f32)
    typedef __attribute__((ext_vector_type(2))) __bf16 bf162_t;
    bf162_t r = __builtin_amdgcn_cvt_pk_bf16_f32(lo, hi);
    return __builtin_bit_cast(unsigned, r);
#else
    return pack2bf16(lo, hi);
#endif
}
__device__ __forceinline__ float fast_exp2(float x) {
#if __has_builtin(__builtin_amdgcn_exp2f)
    return __builtin_amdgcn_exp2f(x);
#else
    return exp2f(x);
#endif
}
__device__ __forceinline__ void dma16(const unsigned short* g, unsigned short* l) {
#if __has_builtin(__builtin_amdgcn_global_load_lds)
    __builtin_amdgcn_global_load_lds(
        (const __attribute__((address_space(1))) unsigned int*)g,
        (__attribute__((address_space(3))) unsigned int*)l, 16, 0, 0);
#else
    const int lane = threadIdx.x & 63;
    *(uint4*)(l + lane * 8) = *(const uint4*)(g);
#endif
}

// ---------------------------------------------------------------------------
// prep (verified R5-R11, absmax 0.5): G = log2e*(ri.rj) + hi + hj via hi/lo
// bf16 splits; PV-DIRECT PERMUTATION bakes the j-order into packA rows so the
// G-pair output regs on lane (q,m) ARE the PV B-fragment. UNCHANGED.
__global__ __launch_bounds__(256) void prep_all(
    const float* __restrict__ U, const float* __restrict__ ref,
    unsigned short* __restrict__ packA, unsigned short* __restrict__ packB,
    unsigned short* __restrict__ utPack)
{
    __shared__ unsigned short tile[64 * 80];
    const int bid = blockIdx.x;
    const int t   = threadIdx.x;

    if (bid < 512) {
        const int gid  = bid * 256 + t;                // 131072 total
        const int half = gid >> 16;                    // 0 = A(j), 1 = B(i)
        const int id   = gid & 0xFFFF;
        const int tile16 = id >> 6;
        const int lane = id & 63;
        const int q    = lane >> 4;
        const int m    = lane & 15;
        const int p = half ? (tile16 * 16 + m)
                           : ((tile16 >> 1) * 32 + (m >> 2) * 8 + (m & 3) + (tile16 & 1) * 4);

        const float* r = ref + (size_t)p * D_REF;
        float rv[5];
        float sq = 0.f;
#pragma unroll
        for (int d = 0; d < 5; ++d) { rv[d] = r[d]; sq += rv[d] * rv[d]; }
        const float h = -0.5f * LOG2E * sq;

        unsigned short bh[5], bl[5];
#pragma unroll
        for (int d = 0; d < 5; ++d) {
            const float base = half ? rv[d] * LOG2E : rv[d];
            bh[d] = bf16rn(base);
            bl[d] = bf16rn(base - bf16tof((unsigned)bh[d]));
        }
        const unsigned short hh  = bf16rn(h);
        const unsigned short hl  = bf16rn(h - bf16tof((unsigned)hh));
        const unsigned short one = 0x3F80;

        unsigned short outv[8];
#pragma unroll
        for (int tt = 0; tt < 8; ++tt) {
            const int k = q * 8 + tt;
            unsigned short v = 0;
            if (!half) {
                if      (k < 5)   v = bh[k];
                else if (k < 10)  v = bh[k - 5];
                else if (k < 15)  v = bl[k - 10];
                else if (k == 15) v = hh;
                else if (k == 16) v = hl;
                else if (k <= 18) v = one;
            } else {
                if      (k < 5)   v = bh[k];
                else if (k < 10)  v = bl[k - 5];
                else if (k < 15)  v = bh[k - 10];
                else if (k <= 16) v = one;
                else if (k == 17) v = hh;
                else if (k == 18) v = hl;
            }
            outv[tt] = v;
        }
        unsigned short* dst = (half ? packB : packA) + ((size_t)tile16 * 64 + lane) * 8;
        *(uint4*)dst = *(uint4*)outv;
    } else {
        const int b  = bid - 512;
        const int j0 = b * 64;
        const int c  = t & 63;
        const int jb = t >> 6;
#pragma unroll
        for (int k = 0; k < 16; ++k) {
            const int jr = jb + k * 4;
            tile[c * 80 + jr] = bf16rn(U[(size_t)(j0 + jr) * C_CH + c]);  // coalesced by c
        }
        __syncthreads();
#pragma unroll
        for (int rep = 0; rep < 2; ++rep) {
            const int id   = rep * 256 + t;            // 512 frag-lanes
            const int lane = id & 63;
            const int ct   = (id >> 6) & 3;
            const int kt   = id >> 8;                  // 0..1
            const int m    = lane & 15;
            const int q    = lane >> 4;
            const uint4 frag = *(const uint4*)&tile[(ct * 16 + m) * 80 + kt * 32 + q * 8];
            const int jtile  = b * 2 + kt;
            *(uint4*)&utPack[(((size_t)jtile * 4 + ct) * 64 + lane) * 8] = frag;
        }
    }
}

// ---------------------------------------------------------------------------
// main (R14): occupancy WITHOUT staging growth. 512-thread blocks (8 waves),
// IBLOCKS=64 (256 i/block): grid 1024 = exactly 4 blocks/CU x 8 waves = 32
// waves/CU potential (vs 13.4 measured R13). The 24 KB chunk stage is shared
// by 8 waves -> 3 dma16/wave; chip-wide L2 staging traffic back to R12 level
// (R13's doubling ate its occupancy gain). Compute per wave identical to R13.
// Theory: VALU(exp2) floor ~83k cyc/SIMD; MFMA+VALU currently serialize
// (sum 95%, no overlap); more resident waves -> cross-wave overlap.
// LDS (shorts): [0,8192) utPack stage | [8192,12288) packA stage. 24 KB.
template<int JS>
__global__ __launch_bounds__(512, 8) void lsh_main(
    const float* __restrict__ U,
    const unsigned short* __restrict__ packA,
    const unsigned short* __restrict__ packB,
    const unsigned short* __restrict__ utPack,
    unsigned short* __restrict__ part,
    float* __restrict__ out,
    int use_part)
{
    constexpr int CHUNKS = (N_PTS / JS) / 128;
    __shared__ __align__(16) unsigned short sh[12288];   // 24 KB

    const int t    = threadIdx.x;
    const int lane = t & 63;
    const int wave = t >> 6;                             // 0..7
    const int q    = lane >> 4;
    const int m    = lane & 15;

    const int ib = blockIdx.x / JS;
    const int js = blockIdx.x % JS;

    bf16x8 bfrag[2];
#pragma unroll
    for (int s = 0; s < 2; ++s) {
        const int itile = ib * 16 + wave * 2 + s;        // 16 i-tiles per block
        bfrag[s] = *(const bf16x8*)(packB + ((size_t)itile * 64 + lane) * 8);
    }

    f32x4 acc[2][4];
#pragma unroll
    for (int s = 0; s < 2; ++s)
#pragma unroll
        for (int ct = 0; ct < 4; ++ct) acc[s][ct] = (f32x4){0.f, 0.f, 0.f, 0.f};

    for (int chunk = 0; chunk < CHUNKS; ++chunk) {
        const unsigned short* srcU = utPack + (size_t)(js * CHUNKS + chunk) * 8192;
        const unsigned short* srcA = packA  + (size_t)(js * CHUNKS + chunk) * 4096;
        __syncthreads();                               // prior chunk's reads done
#pragma unroll
        for (int r = 0; r < 2; ++r)                    // utPack: 16 x 1KB slices
            dma16(srcU + (r * 8 + wave) * 512 + lane * 8, sh + (r * 8 + wave) * 512);
        dma16(srcA + wave * 512 + lane * 8, sh + 8192 + wave * 512);  // packA: 8 slices
        __syncthreads();                               // drains vmcnt -> LDS valid

#pragma unroll
        for (int kt = 0; kt < 4; ++kt) {
            const bf16x8 ga0 = *(const bf16x8*)(sh + 8192 + (kt * 2 + 0) * 512 + lane * 8);
            const bf16x8 ga1 = *(const bf16x8*)(sh + 8192 + (kt * 2 + 1) * 512 + lane * 8);
            bf16x8 uf[4];
#pragma unroll
            for (int ct = 0; ct < 4; ++ct)
                uf[ct] = *(const bf16x8*)(sh + kt * 2048 + ct * 512 + lane * 8);

            const f32x4 z = (f32x4){0.f, 0.f, 0.f, 0.f};
#pragma unroll
            for (int s = 0; s < 2; ++s) {
                const f32x4 g0 = __builtin_amdgcn_mfma_f32_16x16x32_bf16(ga0, bfrag[s], z, 0, 0, 0);
                const f32x4 g1 = __builtin_amdgcn_mfma_f32_16x16x32_bf16(ga1, bfrag[s], z, 0, 0, 0);
                union { unsigned u[4]; bf16x8 v; } sb;
                sb.u[0] = cvt2(fast_exp2(g0[0]), fast_exp2(g0[1]));
                sb.u[1] = cvt2(fast_exp2(g0[2]), fast_exp2(g0[3]));
                sb.u[2] = cvt2(fast_exp2(g1[0]), fast_exp2(g1[1]));
                sb.u[3] = cvt2(fast_exp2(g1[2]), fast_exp2(g1[3]));
#pragma unroll
                for (int ct = 0; ct < 4; ++ct)
                    acc[s][ct] = __builtin_amdgcn_mfma_f32_16x16x32_bf16(
                        uf[ct], sb.v, acc[s][ct], 0, 0, 0);
            }
        }
    }

    if (use_part) {
        // bf16 partials, lane-linear 16 B/lane (fully coalesced, no RMW):
        // short index = (ib*JS+js)*16384 + ((s*2+cp)*512 + t)*8 + cti*4 + r2
        unsigned short* dst = part + ((size_t)ib * JS + js) * 16384;
#pragma unroll
        for (int s = 0; s < 2; ++s)
#pragma unroll
            for (int cp = 0; cp < 2; ++cp) {
                uint4 w;
                w.x = cvt2(acc[s][cp*2+0][0], acc[s][cp*2+0][1]);
                w.y = cvt2(acc[s][cp*2+0][2], acc[s][cp*2+0][3]);
                w.z = cvt2(acc[s][cp*2+1][0], acc[s][cp*2+1][1]);
                w.w = cvt2(acc[s][cp*2+1][2], acc[s][cp*2+1][3]);
                *(uint4*)(dst + ((s * 2 + cp) * 512 + t) * 8) = w;
            }
    } else {
#pragma unroll
        for (int s = 0; s < 2; ++s) {
            const int i_glob = ib * 256 + (wave * 2 + s) * 16 + m;
#pragma unroll
            for (int ct = 0; ct < 4; ++ct)
#pragma unroll
                for (int r2 = 0; r2 < 4; ++r2) {
                    const int c = ct * 16 + q * 4 + r2;
                    float val = acc[s][ct][r2];
                    if (js == 0) val -= U[(size_t)i_glob * C_CH + c];
                    atomicAdd(&out[(size_t)i_glob * C_CH + c], val);
                }
        }
    }
}

// ---------------------------------------------------------------------------
// reduce (R12-proven pattern, 512-thr blocks): block = one (ib, s2cp) pair;
// thread tt reads the EXACT uint4 a writer thread stored -> lane-linear
// 16 B/lane coalesced loads, js-stride 32 KB inside a 512 KB window. Each
// thread reduces 8 channels over JS slices; U-subtraction fused.
template<int JS>
__global__ __launch_bounds__(512) void reduce_part(
    const unsigned short* __restrict__ part, const float* __restrict__ U,
    float* __restrict__ out)
{
    const int ib   = blockIdx.x >> 2;
    const int s2cp = blockIdx.x & 3;
    const int tt   = threadIdx.x;                      // 0..511
    const int s  = s2cp >> 1, cp = s2cp & 1;
    const int wv = tt >> 6, ln = tt & 63, q = ln >> 4, m = ln & 15;
    const int i  = ib * 256 + (wv * 2 + s) * 16 + m;

    float sums[8];
#pragma unroll
    for (int e = 0; e < 8; ++e) sums[e] = 0.f;

    const unsigned short* base =
        part + (size_t)ib * JS * 16384 + (size_t)(s2cp * 512 + tt) * 8;
#pragma unroll
    for (int js = 0; js < JS; ++js) {
        const uint4 w = *(const uint4*)(base + (size_t)js * 16384);
        sums[0] += bf16tof(w.x & 0xFFFFu); sums[1] += bf16tof(w.x >> 16);
        sums[2] += bf16tof(w.y & 0xFFFFu); sums[3] += bf16tof(w.y >> 16);
        sums[4] += bf16tof(w.z & 0xFFFFu); sums[5] += bf16tof(w.z >> 16);
        sums[6] += bf16tof(w.w & 0xFFFFu); sums[7] += bf16tof(w.w >> 16);
    }

#pragma unroll
    for (int cti = 0; cti < 2; ++cti) {
        const int c0 = (cp * 2 + cti) * 16 + q * 4;
        const f32x4 u = *(const f32x4*)(U + (size_t)i * 64 + c0);
        f32x4 r;
        r[0] = sums[cti * 4 + 0] - u[0];
        r[1] = sums[cti * 4 + 1] - u[1];
        r[2] = sums[cti * 4 + 2] - u[2];
        r[3] = sums[cti * 4 + 3] - u[3];
        *(f32x4*)(out + (size_t)i * 64 + c0) = r;
    }
}

extern "C" void kernel_launch(void* const* d_in, const int* in_sizes, int n_in,
                              void* d_out, int out_size, void* d_ws, size_t ws_size,
                              hipStream_t stream) {
    const float* U   = (const float*)d_in[0];
    const float* ref = (const float*)d_in[1];
    float* out = (float*)d_out;

    // ws: utPack 2 MB | packA 1 MB | packB 1 MB | bf16 partials 32 MB (JS=16)
    unsigned short* utPack = (unsigned short*)d_ws;
    unsigned short* packA  = (unsigned short*)((char*)d_ws + (size_t)2 * 1024 * 1024);
    unsigned short* packB  = (unsigned short*)((char*)d_ws + (size_t)3 * 1024 * 1024);
    unsigned short* part   = (unsigned short*)((char*)d_ws + (size_t)4 * 1024 * 1024);

    const size_t MB = 1024 * 1024;
    prep_all<<<768, 256, 0, stream>>>(U, ref, packA, packB, utPack);

    if (ws_size >= 36 * MB) {
        lsh_main<16><<<IBLOCKS * 16, 512, 0, stream>>>(U, packA, packB, utPack,
                                                       part, out, 1);
        reduce_part<16><<<IBLOCKS * 4, 512, 0, stream>>>(part, U, out);
    } else {
        hipMemsetAsync(d_out, 0, (size_t)out_size * sizeof(float), stream);
        lsh_main<8><<<IBLOCKS * 8, 512, 0, stream>>>(U, packA, packB, utPack,
                                                     part, out, 0);
    }
}

// Round 6
// 116.294 us; speedup vs baseline: 2.3646x; 2.3646x over previous
//
#include <hip/hip_runtime.h>
#include <hip/hip_bf16.h>
#include <stdint.h>

#define N_PTS 16384
#define C_CH  64
#define D_REF 5
#define LOG2E 1.44269504088896340736f
#define IBLOCKS 64        // 256 i per block (4 waves x 4 i-tiles x 16)

typedef __attribute__((ext_vector_type(8))) short bf16x8;
typedef __attribute__((ext_vector_type(4))) float f32x4;

__device__ __forceinline__ unsigned short bf16rn(float v) {
    unsigned u = __builtin_bit_cast(unsigned, v) + 0x8000u;   // round-half-up
    return (unsigned short)(u >> 16);
}
__device__ __forceinline__ float bf16tof(unsigned x) {
    return __builtin_bit_cast(float, x << 16);
}
__device__ __forceinline__ unsigned pack2bf16(float lo, float hi) {
    unsigned a = __builtin_bit_cast(unsigned, lo) + 0x8000u;
    unsigned b = __builtin_bit_cast(unsigned, hi) + 0x8000u;
    return __builtin_amdgcn_perm(b, a, 0x07060302u);
}
__device__ __forceinline__ unsigned cvt2(float lo, float hi) {
#if __has_builtin(__builtin_amdgcn_cvt_pk_bf16_f32)
    typedef __attribute__((ext_vector_type(2))) __bf16 bf162_t;
    bf162_t r = __builtin_amdgcn_cvt_pk_bf16_f32(lo, hi);
    return __builtin_bit_cast(unsigned, r);
#else
    return pack2bf16(lo, hi);
#endif
}
__device__ __forceinline__ float fast_exp2(float x) {
#if __has_builtin(__builtin_amdgcn_exp2f)
    return __builtin_amdgcn_exp2f(x);
#else
    return exp2f(x);
#endif
}
__device__ __forceinline__ void dma16(const unsigned short* g, unsigned short* l) {
#if __has_builtin(__builtin_amdgcn_global_load_lds)
    __builtin_amdgcn_global_load_lds(
        (const __attribute__((address_space(1))) unsigned int*)g,
        (__attribute__((address_space(3))) unsigned int*)l, 16, 0, 0);
#else
    const int lane = threadIdx.x & 63;
    *(uint4*)(l + lane * 8) = *(const uint4*)(g);
#endif
}

// ---------------------------------------------------------------------------
// prep (verified R5-R11, absmax 0.5): G = log2e*(ri.rj) + hi + hj via hi/lo
// bf16 splits; PV-DIRECT PERMUTATION bakes the j-order into packA rows so the
// G-pair output regs on lane (q,m) ARE the PV B-fragment. UNCHANGED.
__global__ __launch_bounds__(256) void prep_all(
    const float* __restrict__ U, const float* __restrict__ ref,
    unsigned short* __restrict__ packA, unsigned short* __restrict__ packB,
    unsigned short* __restrict__ utPack)
{
    __shared__ unsigned short tile[64 * 80];
    const int bid = blockIdx.x;
    const int t   = threadIdx.x;

    if (bid < 512) {
        const int gid  = bid * 256 + t;                // 131072 total
        const int half = gid >> 16;                    // 0 = A(j), 1 = B(i)
        const int id   = gid & 0xFFFF;
        const int tile16 = id >> 6;
        const int lane = id & 63;
        const int q    = lane >> 4;
        const int m    = lane & 15;
        const int p = half ? (tile16 * 16 + m)
                           : ((tile16 >> 1) * 32 + (m >> 2) * 8 + (m & 3) + (tile16 & 1) * 4);

        const float* r = ref + (size_t)p * D_REF;
        float rv[5];
        float sq = 0.f;
#pragma unroll
        for (int d = 0; d < 5; ++d) { rv[d] = r[d]; sq += rv[d] * rv[d]; }
        const float h = -0.5f * LOG2E * sq;

        unsigned short bh[5], bl[5];
#pragma unroll
        for (int d = 0; d < 5; ++d) {
            const float base = half ? rv[d] * LOG2E : rv[d];
            bh[d] = bf16rn(base);
            bl[d] = bf16rn(base - bf16tof((unsigned)bh[d]));
        }
        const unsigned short hh  = bf16rn(h);
        const unsigned short hl  = bf16rn(h - bf16tof((unsigned)hh));
        const unsigned short one = 0x3F80;

        unsigned short outv[8];
#pragma unroll
        for (int tt = 0; tt < 8; ++tt) {
            const int k = q * 8 + tt;
            unsigned short v = 0;
            if (!half) {
                if      (k < 5)   v = bh[k];
                else if (k < 10)  v = bh[k - 5];
                else if (k < 15)  v = bl[k - 10];
                else if (k == 15) v = hh;
                else if (k == 16) v = hl;
                else if (k <= 18) v = one;
            } else {
                if      (k < 5)   v = bh[k];
                else if (k < 10)  v = bl[k - 5];
                else if (k < 15)  v = bh[k - 10];
                else if (k <= 16) v = one;
                else if (k == 17) v = hh;
                else if (k == 18) v = hl;
            }
            outv[tt] = v;
        }
        unsigned short* dst = (half ? packB : packA) + ((size_t)tile16 * 64 + lane) * 8;
        *(uint4*)dst = *(uint4*)outv;
    } else {
        const int b  = bid - 512;
        const int j0 = b * 64;
        const int c  = t & 63;
        const int jb = t >> 6;
#pragma unroll
        for (int k = 0; k < 16; ++k) {
            const int jr = jb + k * 4;
            tile[c * 80 + jr] = bf16rn(U[(size_t)(j0 + jr) * C_CH + c]);  // coalesced by c
        }
        __syncthreads();
#pragma unroll
        for (int rep = 0; rep < 2; ++rep) {
            const int id   = rep * 256 + t;            // 512 frag-lanes
            const int lane = id & 63;
            const int ct   = (id >> 6) & 3;
            const int kt   = id >> 8;                  // 0..1
            const int m    = lane & 15;
            const int q    = lane >> 4;
            const uint4 frag = *(const uint4*)&tile[(ct * 16 + m) * 80 + kt * 32 + q * 8];
            const int jtile  = b * 2 + kt;
            *(uint4*)&utPack[(((size_t)jtile * 4 + ct) * 64 + lane) * 8] = frag;
        }
    }
}

// ---------------------------------------------------------------------------
// main (R15): R12-exact structure (verified 116.5us total / 61.5us main:
// 256 thr, 4 waves, acc[4][4], single-buffer 24 KB, 2 barriers/chunk)
// + ONE change: per-block kt-phase rotation. Theory: T = VALU-sum + MFMA-sum
// (143k cyc/SIMD vs max() floor 75k) because co-resident waves are
// phase-locked — all execute exp2 bursts simultaneously, then MFMA bursts.
// rot = (bid + (bid>>8)) & 3 differs across co-resident blocks (~256 apart),
// de-phasing the 4 waves per SIMD so one wave's exp2 overlaps another's MFMA.
// kt order within a staged chunk is arbitrary (f32 accumulation, commutative).
// LDS (shorts): [0,8192) utPack stage | [8192,12288) packA stage. 24 KB.
template<int JS>
__global__ __launch_bounds__(256, 4) void lsh_main(
    const float* __restrict__ U,
    const unsigned short* __restrict__ packA,
    const unsigned short* __restrict__ packB,
    const unsigned short* __restrict__ utPack,
    unsigned short* __restrict__ part,
    float* __restrict__ out,
    int use_part)
{
    constexpr int CHUNKS = (N_PTS / JS) / 128;
    __shared__ __align__(16) unsigned short sh[12288];   // 24 KB

    const int t    = threadIdx.x;
    const int lane = t & 63;
    const int wave = t >> 6;
    const int q    = lane >> 4;
    const int m    = lane & 15;

    const int ib = blockIdx.x / JS;
    const int js = blockIdx.x % JS;
    const int rot = (blockIdx.x + (blockIdx.x >> 8)) & 3;

    bf16x8 bfrag[4];
#pragma unroll
    for (int s = 0; s < 4; ++s) {
        const int itile = ib * 16 + wave * 4 + s;
        bfrag[s] = *(const bf16x8*)(packB + ((size_t)itile * 64 + lane) * 8);
    }

    f32x4 acc[4][4];
#pragma unroll
    for (int s = 0; s < 4; ++s)
#pragma unroll
        for (int ct = 0; ct < 4; ++ct) acc[s][ct] = (f32x4){0.f, 0.f, 0.f, 0.f};

    for (int chunk = 0; chunk < CHUNKS; ++chunk) {
        const unsigned short* srcU = utPack + (size_t)(js * CHUNKS + chunk) * 8192;
        const unsigned short* srcA = packA  + (size_t)(js * CHUNKS + chunk) * 4096;
        __syncthreads();                               // prior chunk's reads done
#pragma unroll
        for (int r = 0; r < 4; ++r)
            dma16(srcU + r * 2048 + wave * 512 + lane * 8, sh + r * 2048 + wave * 512);
#pragma unroll
        for (int r = 0; r < 2; ++r)
            dma16(srcA + r * 2048 + wave * 512 + lane * 8, sh + 8192 + r * 2048 + wave * 512);
        __syncthreads();                               // drains vmcnt -> LDS valid

#pragma unroll
        for (int kti = 0; kti < 4; ++kti) {
            const int kt = (kti + rot) & 3;            // de-phased kt order
            const unsigned short* shA = sh + 8192 + kt * 1024;
            const unsigned short* shU = sh + kt * 2048;
            const bf16x8 ga0 = *(const bf16x8*)(shA + lane * 8);
            const bf16x8 ga1 = *(const bf16x8*)(shA + 512 + lane * 8);

            const f32x4 z = (f32x4){0.f, 0.f, 0.f, 0.f};
            bf16x8 sfrag[4];
#pragma unroll
            for (int s = 0; s < 4; ++s) {
                const f32x4 g0 = __builtin_amdgcn_mfma_f32_16x16x32_bf16(ga0, bfrag[s], z, 0, 0, 0);
                const f32x4 g1 = __builtin_amdgcn_mfma_f32_16x16x32_bf16(ga1, bfrag[s], z, 0, 0, 0);
                union { unsigned u[4]; bf16x8 v; } sb;
                sb.u[0] = cvt2(fast_exp2(g0[0]), fast_exp2(g0[1]));
                sb.u[1] = cvt2(fast_exp2(g0[2]), fast_exp2(g0[3]));
                sb.u[2] = cvt2(fast_exp2(g1[0]), fast_exp2(g1[1]));
                sb.u[3] = cvt2(fast_exp2(g1[2]), fast_exp2(g1[3]));
                sfrag[s] = sb.v;                       // == PV B-frag for 32 j
            }
#pragma unroll
            for (int ct = 0; ct < 4; ++ct) {
                const bf16x8 uf = *(const bf16x8*)(shU + ct * 512 + lane * 8);
#pragma unroll
                for (int s = 0; s < 4; ++s)
                    acc[s][ct] = __builtin_amdgcn_mfma_f32_16x16x32_bf16(
                        uf, sfrag[s], acc[s][ct], 0, 0, 0);
            }
        }
    }

    if (use_part) {
        // bf16 partials, lane-linear 16 B/lane (fully coalesced, no RMW):
        // short index = (ib*JS+js)*16384 + ((s*2+cp)*256 + t)*8 + cti*4 + r2
        unsigned short* dst = part + ((size_t)ib * JS + js) * 16384;
#pragma unroll
        for (int s = 0; s < 4; ++s)
#pragma unroll
            for (int cp = 0; cp < 2; ++cp) {
                uint4 w;
                w.x = cvt2(acc[s][cp*2+0][0], acc[s][cp*2+0][1]);
                w.y = cvt2(acc[s][cp*2+0][2], acc[s][cp*2+0][3]);
                w.z = cvt2(acc[s][cp*2+1][0], acc[s][cp*2+1][1]);
                w.w = cvt2(acc[s][cp*2+1][2], acc[s][cp*2+1][3]);
                *(uint4*)(dst + ((s * 2 + cp) * 256 + t) * 8) = w;
            }
    } else {
#pragma unroll
        for (int s = 0; s < 4; ++s) {
            const int i_glob = ib * 256 + (wave * 4 + s) * 16 + m;
#pragma unroll
            for (int ct = 0; ct < 4; ++ct)
#pragma unroll
                for (int r2 = 0; r2 < 4; ++r2) {
                    const int c = ct * 16 + q * 4 + r2;
                    float val = acc[s][ct][r2];
                    if (js == 0) val -= U[(size_t)i_glob * C_CH + c];
                    atomicAdd(&out[(size_t)i_glob * C_CH + c], val);
                }
        }
    }
}

// ---------------------------------------------------------------------------
// reduce (R12-proven): block = one (ib, s2cp) pair; thread tt reads the EXACT
// uint4 a writer thread stored -> lane-linear 16 B/lane coalesced loads with
// 32 KB js-stride inside a 256 KB window. Each thread reduces 8 channels over
// JS slices and writes two f32x4 with the U-subtraction fused.
template<int JS>
__global__ __launch_bounds__(256) void reduce_part(
    const unsigned short* __restrict__ part, const float* __restrict__ U,
    float* __restrict__ out)
{
    const int ib   = blockIdx.x >> 3;
    const int s2cp = blockIdx.x & 7;
    const int tt   = threadIdx.x;
    const int s  = s2cp >> 1, cp = s2cp & 1;
    const int wv = tt >> 6, ln = tt & 63, q = ln >> 4, m = ln & 15;
    const int i  = ib * 256 + (wv * 4 + s) * 16 + m;

    float sums[8];
#pragma unroll
    for (int e = 0; e < 8; ++e) sums[e] = 0.f;

    const unsigned short* base =
        part + (size_t)ib * JS * 16384 + (size_t)(s2cp * 256 + tt) * 8;
#pragma unroll
    for (int js = 0; js < JS; ++js) {
        const uint4 w = *(const uint4*)(base + (size_t)js * 16384);
        sums[0] += bf16tof(w.x & 0xFFFFu); sums[1] += bf16tof(w.x >> 16);
        sums[2] += bf16tof(w.y & 0xFFFFu); sums[3] += bf16tof(w.y >> 16);
        sums[4] += bf16tof(w.z & 0xFFFFu); sums[5] += bf16tof(w.z >> 16);
        sums[6] += bf16tof(w.w & 0xFFFFu); sums[7] += bf16tof(w.w >> 16);
    }

#pragma unroll
    for (int cti = 0; cti < 2; ++cti) {
        const int c0 = (cp * 2 + cti) * 16 + q * 4;
        const f32x4 u = *(const f32x4*)(U + (size_t)i * 64 + c0);
        f32x4 r;
        r[0] = sums[cti * 4 + 0] - u[0];
        r[1] = sums[cti * 4 + 1] - u[1];
        r[2] = sums[cti * 4 + 2] - u[2];
        r[3] = sums[cti * 4 + 3] - u[3];
        *(f32x4*)(out + (size_t)i * 64 + c0) = r;
    }
}

extern "C" void kernel_launch(void* const* d_in, const int* in_sizes, int n_in,
                              void* d_out, int out_size, void* d_ws, size_t ws_size,
                              hipStream_t stream) {
    const float* U   = (const float*)d_in[0];
    const float* ref = (const float*)d_in[1];
    float* out = (float*)d_out;

    // ws: utPack 2 MB | packA 1 MB | packB 1 MB | bf16 partials 32 MB (JS=16)
    unsigned short* utPack = (unsigned short*)d_ws;
    unsigned short* packA  = (unsigned short*)((char*)d_ws + (size_t)2 * 1024 * 1024);
    unsigned short* packB  = (unsigned short*)((char*)d_ws + (size_t)3 * 1024 * 1024);
    unsigned short* part   = (unsigned short*)((char*)d_ws + (size_t)4 * 1024 * 1024);

    const size_t MB = 1024 * 1024;
    prep_all<<<768, 256, 0, stream>>>(U, ref, packA, packB, utPack);

    if (ws_size >= 36 * MB) {
        lsh_main<16><<<IBLOCKS * 16, 256, 0, stream>>>(U, packA, packB, utPack,
                                                       part, out, 1);
        reduce_part<16><<<512, 256, 0, stream>>>(part, U, out);
    } else {
        hipMemsetAsync(d_out, 0, (size_t)out_size * sizeof(float), stream);
        lsh_main<8><<<IBLOCKS * 8, 256, 0, stream>>>(U, packA, packB, utPack,
                                                     part, out, 0);
    }
}

// Round 7
// 115.386 us; speedup vs baseline: 2.3832x; 1.0079x over previous
//
#include <hip/hip_runtime.h>
#include <hip/hip_bf16.h>
#include <stdint.h>

#define N_PTS 16384
#define C_CH  64
#define D_REF 5
#define LOG2E 1.44269504088896340736f
#define IBLOCKS 64        // 256 i per block (4 waves x 4 i-tiles x 16)

typedef __attribute__((ext_vector_type(8))) short bf16x8;
typedef __attribute__((ext_vector_type(4))) float f32x4;

__device__ __forceinline__ unsigned short bf16rn(float v) {
    unsigned u = __builtin_bit_cast(unsigned, v) + 0x8000u;   // round-half-up
    return (unsigned short)(u >> 16);
}
__device__ __forceinline__ float bf16tof(unsigned x) {
    return __builtin_bit_cast(float, x << 16);
}
__device__ __forceinline__ unsigned pack2bf16(float lo, float hi) {
    unsigned a = __builtin_bit_cast(unsigned, lo) + 0x8000u;
    unsigned b = __builtin_bit_cast(unsigned, hi) + 0x8000u;
    return __builtin_amdgcn_perm(b, a, 0x07060302u);
}
__device__ __forceinline__ unsigned cvt2(float lo, float hi) {
#if __has_builtin(__builtin_amdgcn_cvt_pk_bf16_f32)
    typedef __attribute__((ext_vector_type(2))) __bf16 bf162_t;
    bf162_t r = __builtin_amdgcn_cvt_pk_bf16_f32(lo, hi);
    return __builtin_bit_cast(unsigned, r);
#else
    return pack2bf16(lo, hi);
#endif
}
__device__ __forceinline__ float fast_exp2(float x) {
#if __has_builtin(__builtin_amdgcn_exp2f)
    return __builtin_amdgcn_exp2f(x);
#else
    return exp2f(x);
#endif
}
__device__ __forceinline__ void dma16(const unsigned short* g, unsigned short* l) {
#if __has_builtin(__builtin_amdgcn_global_load_lds)
    __builtin_amdgcn_global_load_lds(
        (const __attribute__((address_space(1))) unsigned int*)g,
        (__attribute__((address_space(3))) unsigned int*)l, 16, 0, 0);
#else
    const int lane = threadIdx.x & 63;
    *(uint4*)(l + lane * 8) = *(const uint4*)(g);
#endif
}

// ---------------------------------------------------------------------------
// prep (verified R5-R11, absmax 0.5): G = log2e*(ri.rj) + hi + hj via hi/lo
// bf16 splits; PV-DIRECT PERMUTATION bakes the j-order into packA rows so the
// G-pair output regs on lane (q,m) ARE the PV B-fragment. UNCHANGED.
__global__ __launch_bounds__(256) void prep_all(
    const float* __restrict__ U, const float* __restrict__ ref,
    unsigned short* __restrict__ packA, unsigned short* __restrict__ packB,
    unsigned short* __restrict__ utPack)
{
    __shared__ unsigned short tile[64 * 80];
    const int bid = blockIdx.x;
    const int t   = threadIdx.x;

    if (bid < 512) {
        const int gid  = bid * 256 + t;                // 131072 total
        const int half = gid >> 16;                    // 0 = A(j), 1 = B(i)
        const int id   = gid & 0xFFFF;
        const int tile16 = id >> 6;
        const int lane = id & 63;
        const int q    = lane >> 4;
        const int m    = lane & 15;
        const int p = half ? (tile16 * 16 + m)
                           : ((tile16 >> 1) * 32 + (m >> 2) * 8 + (m & 3) + (tile16 & 1) * 4);

        const float* r = ref + (size_t)p * D_REF;
        float rv[5];
        float sq = 0.f;
#pragma unroll
        for (int d = 0; d < 5; ++d) { rv[d] = r[d]; sq += rv[d] * rv[d]; }
        const float h = -0.5f * LOG2E * sq;

        unsigned short bh[5], bl[5];
#pragma unroll
        for (int d = 0; d < 5; ++d) {
            const float base = half ? rv[d] * LOG2E : rv[d];
            bh[d] = bf16rn(base);
            bl[d] = bf16rn(base - bf16tof((unsigned)bh[d]));
        }
        const unsigned short hh  = bf16rn(h);
        const unsigned short hl  = bf16rn(h - bf16tof((unsigned)hh));
        const unsigned short one = 0x3F80;

        unsigned short outv[8];
#pragma unroll
        for (int tt = 0; tt < 8; ++tt) {
            const int k = q * 8 + tt;
            unsigned short v = 0;
            if (!half) {
                if      (k < 5)   v = bh[k];
                else if (k < 10)  v = bh[k - 5];
                else if (k < 15)  v = bl[k - 10];
                else if (k == 15) v = hh;
                else if (k == 16) v = hl;
                else if (k <= 18) v = one;
            } else {
                if      (k < 5)   v = bh[k];
                else if (k < 10)  v = bl[k - 5];
                else if (k < 15)  v = bh[k - 10];
                else if (k <= 16) v = one;
                else if (k == 17) v = hh;
                else if (k == 18) v = hl;
            }
            outv[tt] = v;
        }
        unsigned short* dst = (half ? packB : packA) + ((size_t)tile16 * 64 + lane) * 8;
        *(uint4*)dst = *(uint4*)outv;
    } else {
        const int b  = bid - 512;
        const int j0 = b * 64;
        const int c  = t & 63;
        const int jb = t >> 6;
#pragma unroll
        for (int k = 0; k < 16; ++k) {
            const int jr = jb + k * 4;
            tile[c * 80 + jr] = bf16rn(U[(size_t)(j0 + jr) * C_CH + c]);  // coalesced by c
        }
        __syncthreads();
#pragma unroll
        for (int rep = 0; rep < 2; ++rep) {
            const int id   = rep * 256 + t;            // 512 frag-lanes
            const int lane = id & 63;
            const int ct   = (id >> 6) & 3;
            const int kt   = id >> 8;                  // 0..1
            const int m    = lane & 15;
            const int q    = lane >> 4;
            const uint4 frag = *(const uint4*)&tile[(ct * 16 + m) * 80 + kt * 32 + q * 8];
            const int jtile  = b * 2 + kt;
            *(uint4*)&utPack[(((size_t)jtile * 4 + ct) * 64 + lane) * 8] = frag;
        }
    }
}

// ---------------------------------------------------------------------------
// main (R16): double-buffered staging + counted vmcnt (T3/T4-lite), SAME
// 24 KB LDS and SAME chip-wide traffic as R12. Theory: pipes are unsaturated
// (VALUBusy 53 / MfmaUtil 35, occ register-capped at 4 waves/SIMD) -> the
// loss is the per-chunk {issue DMA -> vmcnt(0) drain -> barrier} serial stall
// (m233: 2-phase stage overhead dominates). Fix: 64-j chunks (12 KB), 2 bufs;
// per chunk: barrier -> issue next chunk's 3 DMAs into buf^1 -> vmcnt(3)
// (waits only loads issued one full compute-phase ago -> ~0 stall) -> barrier
// -> compute. Staging latency hides under the previous chunk's compute.
// Per-buf layout (shorts): [0,4096) utPack (64j x 64c) | [4096,6144) packA.
template<int JS>
__global__ __launch_bounds__(256, 4) void lsh_main(
    const float* __restrict__ U,
    const unsigned short* __restrict__ packA,
    const unsigned short* __restrict__ packB,
    const unsigned short* __restrict__ utPack,
    unsigned short* __restrict__ part,
    float* __restrict__ out,
    int use_part)
{
    constexpr int CHUNKS = (N_PTS / JS) / 64;            // 64-j chunks
    __shared__ __align__(16) unsigned short sh[2][6144]; // 24 KB total

    const int t    = threadIdx.x;
    const int lane = t & 63;
    const int wave = t >> 6;
    const int q    = lane >> 4;
    const int m    = lane & 15;

    const int ib = blockIdx.x / JS;
    const int js = blockIdx.x % JS;

    bf16x8 bfrag[4];
#pragma unroll
    for (int s = 0; s < 4; ++s) {
        const int itile = ib * 16 + wave * 4 + s;
        bfrag[s] = *(const bf16x8*)(packB + ((size_t)itile * 64 + lane) * 8);
    }

    f32x4 acc[4][4];
#pragma unroll
    for (int s = 0; s < 4; ++s)
#pragma unroll
        for (int ct = 0; ct < 4; ++ct) acc[s][ct] = (f32x4){0.f, 0.f, 0.f, 0.f};

    // prologue: stage chunk 0 into buf 0 (3 DMAs/thread)
    {
        const unsigned short* srcU = utPack + (size_t)(js * CHUNKS) * 4096;
        const unsigned short* srcA = packA  + (size_t)(js * CHUNKS) * 2048;
        dma16(srcU + wave * 512 + lane * 8,        &sh[0][0] + wave * 512);
        dma16(srcU + 2048 + wave * 512 + lane * 8, &sh[0][0] + 2048 + wave * 512);
        dma16(srcA + wave * 512 + lane * 8,        &sh[0][4096] + wave * 512);
    }

    for (int chunk = 0; chunk < CHUNKS; ++chunk) {
        const int cur = chunk & 1;
        __builtin_amdgcn_s_barrier();          // readers of sh[cur^1] (iter-1) done
        if (chunk + 1 < CHUNKS) {
            const unsigned short* srcU = utPack + (size_t)(js * CHUNKS + chunk + 1) * 4096;
            const unsigned short* srcA = packA  + (size_t)(js * CHUNKS + chunk + 1) * 2048;
            unsigned short* dst = &sh[cur ^ 1][0];
            dma16(srcU + wave * 512 + lane * 8,        dst + wave * 512);
            dma16(srcU + 2048 + wave * 512 + lane * 8, dst + 2048 + wave * 512);
            dma16(srcA + wave * 512 + lane * 8,        dst + 4096 + wave * 512);
            asm volatile("s_waitcnt vmcnt(3)" ::: "memory");   // chunk k's 3 landed
        } else {
            asm volatile("s_waitcnt vmcnt(0)" ::: "memory");
        }
        __builtin_amdgcn_s_barrier();          // all waves' sh[cur] staged

        const unsigned short* buf = &sh[cur][0];
#pragma unroll
        for (int kt = 0; kt < 2; ++kt) {
            const bf16x8 ga0 = *(const bf16x8*)(buf + 4096 + kt * 1024 + lane * 8);
            const bf16x8 ga1 = *(const bf16x8*)(buf + 4096 + kt * 1024 + 512 + lane * 8);

            const f32x4 z = (f32x4){0.f, 0.f, 0.f, 0.f};
            bf16x8 sfrag[4];
#pragma unroll
            for (int s = 0; s < 4; ++s) {
                const f32x4 g0 = __builtin_amdgcn_mfma_f32_16x16x32_bf16(ga0, bfrag[s], z, 0, 0, 0);
                const f32x4 g1 = __builtin_amdgcn_mfma_f32_16x16x32_bf16(ga1, bfrag[s], z, 0, 0, 0);
                union { unsigned u[4]; bf16x8 v; } sb;
                sb.u[0] = cvt2(fast_exp2(g0[0]), fast_exp2(g0[1]));
                sb.u[1] = cvt2(fast_exp2(g0[2]), fast_exp2(g0[3]));
                sb.u[2] = cvt2(fast_exp2(g1[0]), fast_exp2(g1[1]));
                sb.u[3] = cvt2(fast_exp2(g1[2]), fast_exp2(g1[3]));
                sfrag[s] = sb.v;                       // == PV B-frag for 32 j
            }
#pragma unroll
            for (int ct = 0; ct < 4; ++ct) {
                const bf16x8 uf = *(const bf16x8*)(buf + kt * 2048 + ct * 512 + lane * 8);
#pragma unroll
                for (int s = 0; s < 4; ++s)
                    acc[s][ct] = __builtin_amdgcn_mfma_f32_16x16x32_bf16(
                        uf, sfrag[s], acc[s][ct], 0, 0, 0);
            }
        }
    }

    if (use_part) {
        // bf16 partials, lane-linear 16 B/lane (fully coalesced, no RMW):
        // short index = (ib*JS+js)*16384 + ((s*2+cp)*256 + t)*8 + cti*4 + r2
        unsigned short* dst = part + ((size_t)ib * JS + js) * 16384;
#pragma unroll
        for (int s = 0; s < 4; ++s)
#pragma unroll
            for (int cp = 0; cp < 2; ++cp) {
                uint4 w;
                w.x = cvt2(acc[s][cp*2+0][0], acc[s][cp*2+0][1]);
                w.y = cvt2(acc[s][cp*2+0][2], acc[s][cp*2+0][3]);
                w.z = cvt2(acc[s][cp*2+1][0], acc[s][cp*2+1][1]);
                w.w = cvt2(acc[s][cp*2+1][2], acc[s][cp*2+1][3]);
                *(uint4*)(dst + ((s * 2 + cp) * 256 + t) * 8) = w;
            }
    } else {
#pragma unroll
        for (int s = 0; s < 4; ++s) {
            const int i_glob = ib * 256 + (wave * 4 + s) * 16 + m;
#pragma unroll
            for (int ct = 0; ct < 4; ++ct)
#pragma unroll
                for (int r2 = 0; r2 < 4; ++r2) {
                    const int c = ct * 16 + q * 4 + r2;
                    float val = acc[s][ct][r2];
                    if (js == 0) val -= U[(size_t)i_glob * C_CH + c];
                    atomicAdd(&out[(size_t)i_glob * C_CH + c], val);
                }
        }
    }
}

// ---------------------------------------------------------------------------
// reduce (R12-proven): block = one (ib, s2cp) pair; thread tt reads the EXACT
// uint4 a writer thread stored -> lane-linear 16 B/lane coalesced loads with
// 32 KB js-stride inside a 256 KB window. Each thread reduces 8 channels over
// JS slices and writes two f32x4 with the U-subtraction fused.
template<int JS>
__global__ __launch_bounds__(256) void reduce_part(
    const unsigned short* __restrict__ part, const float* __restrict__ U,
    float* __restrict__ out)
{
    const int ib   = blockIdx.x >> 3;
    const int s2cp = blockIdx.x & 7;
    const int tt   = threadIdx.x;
    const int s  = s2cp >> 1, cp = s2cp & 1;
    const int wv = tt >> 6, ln = tt & 63, q = ln >> 4, m = ln & 15;
    const int i  = ib * 256 + (wv * 4 + s) * 16 + m;

    float sums[8];
#pragma unroll
    for (int e = 0; e < 8; ++e) sums[e] = 0.f;

    const unsigned short* base =
        part + (size_t)ib * JS * 16384 + (size_t)(s2cp * 256 + tt) * 8;
#pragma unroll
    for (int js = 0; js < JS; ++js) {
        const uint4 w = *(const uint4*)(base + (size_t)js * 16384);
        sums[0] += bf16tof(w.x & 0xFFFFu); sums[1] += bf16tof(w.x >> 16);
        sums[2] += bf16tof(w.y & 0xFFFFu); sums[3] += bf16tof(w.y >> 16);
        sums[4] += bf16tof(w.z & 0xFFFFu); sums[5] += bf16tof(w.z >> 16);
        sums[6] += bf16tof(w.w & 0xFFFFu); sums[7] += bf16tof(w.w >> 16);
    }

#pragma unroll
    for (int cti = 0; cti < 2; ++cti) {
        const int c0 = (cp * 2 + cti) * 16 + q * 4;
        const f32x4 u = *(const f32x4*)(U + (size_t)i * 64 + c0);
        f32x4 r;
        r[0] = sums[cti * 4 + 0] - u[0];
        r[1] = sums[cti * 4 + 1] - u[1];
        r[2] = sums[cti * 4 + 2] - u[2];
        r[3] = sums[cti * 4 + 3] - u[3];
        *(f32x4*)(out + (size_t)i * 64 + c0) = r;
    }
}

extern "C" void kernel_launch(void* const* d_in, const int* in_sizes, int n_in,
                              void* d_out, int out_size, void* d_ws, size_t ws_size,
                              hipStream_t stream) {
    const float* U   = (const float*)d_in[0];
    const float* ref = (const float*)d_in[1];
    float* out = (float*)d_out;

    // ws: utPack 2 MB | packA 1 MB | packB 1 MB | bf16 partials 32 MB (JS=16)
    unsigned short* utPack = (unsigned short*)d_ws;
    unsigned short* packA  = (unsigned short*)((char*)d_ws + (size_t)2 * 1024 * 1024);
    unsigned short* packB  = (unsigned short*)((char*)d_ws + (size_t)3 * 1024 * 1024);
    unsigned short* part   = (unsigned short*)((char*)d_ws + (size_t)4 * 1024 * 1024);

    const size_t MB = 1024 * 1024;
    prep_all<<<768, 256, 0, stream>>>(U, ref, packA, packB, utPack);

    if (ws_size >= 36 * MB) {
        lsh_main<16><<<IBLOCKS * 16, 256, 0, stream>>>(U, packA, packB, utPack,
                                                       part, out, 1);
        reduce_part<16><<<512, 256, 0, stream>>>(part, U, out);
    } else {
        hipMemsetAsync(d_out, 0, (size_t)out_size * sizeof(float), stream);
        lsh_main<8><<<IBLOCKS * 8, 256, 0, stream>>>(U, packA, packB, utPack,
                                                     part, out, 0);
    }
}